// Round 17
// baseline (391.902 us; speedup 1.0000x reference)
//
#include <hip/hip_runtime.h>
#include <stdint.h>

// SNN audio classifier. Round 17 = round 16 (367us) with two VALU cuts:
//  (1) phase A odd-window v2f pairing restored (round-15-verified wo0..wo5):
//      a1 = 6 pkfma + fma + add instead of 13 serial fmaf (+12 VGPR, ~116<128).
//  (2) phase B packed reduction: 4 scalar dpp_add8 trees -> 2 packed v2f trees
//      (mov_dpp x2 + v_pk_add_f32 per stage; per-component add order identical
//      -> bit-exact). ~60 fewer VALU slots/lane-step on the 66%-busy pipe.

#define NB 512
#define NT 100
#define LIN 686
#define RS 82          // spool row stride in v2f

typedef float v2f __attribute__((ext_vector_type(2)));

__device__ __forceinline__ v2f pkfma(v2f a, v2f b, v2f c) {
    v2f d;
    asm("v_pk_fma_f32 %0, %1, %2, %3" : "=v"(d) : "v"(a), "v"(b), "v"(c));
    return d;
}

__device__ __forceinline__ v2f pkadd(v2f a, v2f b) {
    v2f d;
    asm("v_pk_add_f32 %0, %1, %2" : "=v"(d) : "v"(a), "v"(b));
    return d;
}

__device__ __forceinline__ float dpp_add8(float x) {   // sum over 8-lane groups
    int t;
    t = __builtin_amdgcn_mov_dpp(__float_as_int(x), 0x141, 0xf, 0xf, true); // row_half_mirror
    x += __int_as_float(t);
    t = __builtin_amdgcn_mov_dpp(__float_as_int(x), 0x1B, 0xf, 0xf, true);  // quad_perm [3,2,1,0]
    x += __int_as_float(t);
    t = __builtin_amdgcn_mov_dpp(__float_as_int(x), 0xB1, 0xf, 0xf, true);  // quad_perm [1,0,3,2]
    x += __int_as_float(t);
    return x;
}

__device__ __forceinline__ v2f dpp_add8_pk(v2f x) {    // packed pair of 8-lane sums
    v2f t;
    t.x = __int_as_float(__builtin_amdgcn_mov_dpp(__float_as_int(x.x), 0x141, 0xf, 0xf, true));
    t.y = __int_as_float(__builtin_amdgcn_mov_dpp(__float_as_int(x.y), 0x141, 0xf, 0xf, true));
    x = pkadd(x, t);
    t.x = __int_as_float(__builtin_amdgcn_mov_dpp(__float_as_int(x.x), 0x1B, 0xf, 0xf, true));
    t.y = __int_as_float(__builtin_amdgcn_mov_dpp(__float_as_int(x.y), 0x1B, 0xf, 0xf, true));
    x = pkadd(x, t);
    t.x = __int_as_float(__builtin_amdgcn_mov_dpp(__float_as_int(x.x), 0xB1, 0xf, 0xf, true));
    t.y = __int_as_float(__builtin_amdgcn_mov_dpp(__float_as_int(x.y), 0xB1, 0xf, 0xf, true));
    x = pkadd(x, t);
    return x;
}

__device__ __forceinline__ float red32(float x) {      // sum over 32-lane groups
    int t;
    t = __builtin_amdgcn_mov_dpp(__float_as_int(x), 0xB1, 0xf, 0xf, true);  // xor1
    x += __int_as_float(t);
    t = __builtin_amdgcn_mov_dpp(__float_as_int(x), 0x4E, 0xf, 0xf, true);  // xor2
    x += __int_as_float(t);
    t = __builtin_amdgcn_mov_dpp(__float_as_int(x), 0x124, 0xf, 0xf, true); // row_ror:4
    x += __int_as_float(t);
    t = __builtin_amdgcn_mov_dpp(__float_as_int(x), 0x128, 0xf, 0xf, true); // row_ror:8
    x += __int_as_float(t);
    t = __builtin_amdgcn_ds_swizzle(__float_as_int(x), 0x401F);             // xor16
    x += __int_as_float(t);
    return x;
}

// bit(o) of the published spk2 ballots (512-thr layout, round-13-verified)
#define FBIT(W1L, W1H, W2L, W2H, o) \
    ((float)(((((o) < 16) ? ((((o) >> 2) & 1) ? (W1H) : (W1L)) \
                          : ((((o) >> 2) & 1) ? (W2H) : (W2L))) >> \
              (((o) < 16) ? (4 * (((o) >> 3) & 1) + 8 * ((o) & 3)) : (8 * ((o) & 3)))) & 1u))

__global__
__attribute__((amdgpu_flat_work_group_size(512, 512)))
__attribute__((amdgpu_waves_per_eu(1, 2)))
void snn_all(
    const float* __restrict__ x,
    const float* __restrict__ w1, const float* __restrict__ b1,
    const float* __restrict__ w2, const float* __restrict__ b2,
    const float* __restrict__ wf1, const float* __restrict__ bf1,
    const float* __restrict__ wf2, const float* __restrict__ bf2,
    float* __restrict__ out)
{
    __shared__ __align__(16) float swf1r[5632 * 4];            // 90112 B, shared
    __shared__ __align__(16) float sx[2][LIN + 2];
    __shared__ __align__(16) float spool2f[2][8 * RS * 2];
    __shared__ unsigned long long sbits[2][8][2];
    __shared__ __align__(8) float sspk3[2][32];

    const int t2   = threadIdx.x;      // 0..511
    const int b0   = blockIdx.x * 2;   // this block's two samples
    const int lane = t2 & 63;
    const int wv   = t2 >> 6;          // wave 0..7

    // ---------------- one-time init: reorder wf1 into LDS ----------------
    for (int d = t2; d < 5632; d += 512) {
        int g = d / 352;
        int r = d - g * 352;
        int i = r >> 5;
        int s = r & 31;
        float4 v;
        v.x = wf1[(2 * g)     * 704 + s * 22 + 2 * i];
        v.y = wf1[(2 * g)     * 704 + s * 22 + 2 * i + 1];
        v.z = wf1[(2 * g + 1) * 704 + s * 22 + 2 * i];
        v.w = wf1[(2 * g + 1) * 704 + s * 22 + 2 * i + 1];
        reinterpret_cast<float4*>(swf1r)[d] = v;
    }

    // ---- phase A setup: conv1. thread = (ca = t2&15, pg = t2>>4 in 0..31) ----
    const int ca = t2 & 15;
    const int pg = t2 >> 4;
    float wAs[13];
    #pragma unroll
    for (int k = 0; k < 13; ++k) wAs[k] = w1[ca * 13 + k];
    v2f we0 = {wAs[0], wAs[1]}, we1 = {wAs[2], wAs[3]}, we2 = {wAs[4], wAs[5]},
        we3 = {wAs[6], wAs[7]}, we4 = {wAs[8], wAs[9]}, we5 = {wAs[10], wAs[11]};
    v2f wo0 = {wAs[1], wAs[2]}, wo1 = {wAs[3], wAs[4]}, wo2 = {wAs[5], wAs[6]},
        wo3 = {wAs[7], wAs[8]}, wo4 = {wAs[9], wAs[10]}, wo5 = {wAs[11], wAs[12]};
    const float wA0s = wAs[0], wA12s = wAs[12];
    const float bA = b1[ca];
    float m1a0[3], m1b0[3], m1a1[3], m1b1[3];
    #pragma unroll
    for (int j = 0; j < 3; ++j) { m1a0[j] = 0.f; m1b0[j] = 0.f; m1a1[j] = 0.f; m1b1[j] = 0.f; }

    // ---- phase B setup: conv2. wave wv owns channel quartet 4wv..4wv+3 ----
    const int ip  = lane & 7;          // row-pair (conv1 rows 2ip, 2ip+1)
    const int og  = (lane >> 3) & 3;   // output phase
    const int omh = lane >> 5;         // window triple: om = {omh, 2+omh, 4+omh}
    const int ccq = ip & 3;            // owned channel within quartet
    v2f wp0[7], wp1[7], wp2[7], wp3[7];
    #pragma unroll
    for (int k = 0; k < 7; ++k) {
        int base0 = (wv * 4 + 0) * 112 + 14 * ip + k;
        int base1 = (wv * 4 + 1) * 112 + 14 * ip + k;
        int base2 = (wv * 4 + 2) * 112 + 14 * ip + k;
        int base3 = (wv * 4 + 3) * 112 + 14 * ip + k;
        wp0[k].x = w2[base0]; wp0[k].y = w2[base0 + 7];
        wp1[k].x = w2[base1]; wp1[k].y = w2[base1 + 7];
        wp2[k].x = w2[base2]; wp2[k].y = w2[base2 + 7];
        wp3[k].x = w2[base3]; wp3[k].y = w2[base3 + 7];
    }
    const float bB = b2[wv * 4 + ccq];
    float mA0 = 0.f, mB0 = 0.f, mA1 = 0.f, mB1 = 0.f;

    // ---- phase C setup: group gC = wv*2 + sub handles outputs 2gC, 2gC+1 ----
    const int sub = (t2 >> 5) & 1;
    const int gC  = wv * 2 + sub;
    const int s_  = t2 & 31;
    const float bC0 = bf1[2 * gC], bC1 = bf1[2 * gC + 1];
    float m30_0 = 0.f, m31_0 = 0.f, m30_1 = 0.f, m31_1 = 0.f;
    const int q_  = s_ >> 2;
    const int cc_ = s_ & 3;

    // ---- phase D setup: fc2 ----
    float wD = 0.f, bD = 0.f;
    if (t2 < 64) {
        wD = wf2[(t2 >> 5) * 32 + (t2 & 31)];
        if ((t2 & 31) == 0) bD = bf2[t2 >> 5];
    }
    float m4_0 = 0.f, cnt_0 = 0.f, m4_1 = 0.f, cnt_1 = 0.f;

    // ---- init LDS ----
    for (int i = t2; i < 2 * 8 * RS * 2; i += 512) ((float*)spool2f)[i] = 0.f;
    const float* xb0p = x + (size_t)b0 * NT * LIN;
    const float* xb1p = xb0p + (size_t)NT * LIN;
    if (t2 == 0) { sx[0][0] = 0.f; sx[0][LIN + 1] = 0.f; sx[1][0] = 0.f; sx[1][LIN + 1] = 0.f; }
    sx[0][1 + t2] = xb0p[t2];
    sx[1][1 + t2] = xb1p[t2];
    if (t2 < LIN - 512) {
        sx[0][1 + t2 + 512] = xb0p[t2 + 512];
        sx[1][1 + t2 + 512] = xb1p[t2 + 512];
    }
    __syncthreads();

    const v2f* sp0v = reinterpret_cast<const v2f*>(spool2f[0]);
    const v2f* sp1v = reinterpret_cast<const v2f*>(spool2f[1]);
    const v2f* wbA  = sp0v + ip * RS + 3 * og + 12 * omh;
    const v2f* wbB  = sp1v + ip * RS + 3 * og + 12 * omh;
    const float4* wrow = reinterpret_cast<const float4*>(swf1r) + gC * 352 + s_;

// ===== phase A (3-slot): conv1 + LIF1 + maxpool2, dual v2f pairings =====
#define A_J3(j, SXH, SPOOLH, M1A, M1B) { \
    const int p_ = ((j) == 2) ? (64 + pg) : (pg + 32 * (j)); \
    if ((j) < 2 || pg < 4) { \
        const v2f* qv_ = reinterpret_cast<const v2f*>((SXH) + 10 * p_); \
        v2f q0_ = qv_[0], q1_ = qv_[1], q2_ = qv_[2], q3_ = qv_[3], q4_ = qv_[4], \
            q5_ = qv_[5], q6_ = qv_[6], q7_ = qv_[7], q8_ = qv_[8]; \
        v2f va_ = {0.f, 0.f}, vb_ = {0.f, 0.f}; \
        va_ = pkfma(we0, q0_, va_); va_ = pkfma(we1, q1_, va_); \
        va_ = pkfma(we2, q2_, va_); va_ = pkfma(we3, q3_, va_); \
        va_ = pkfma(we4, q4_, va_); va_ = pkfma(we5, q5_, va_); \
        vb_ = pkfma(wo0, q3_, vb_); vb_ = pkfma(wo1, q4_, vb_); \
        vb_ = pkfma(wo2, q5_, vb_); vb_ = pkfma(wo3, q6_, vb_); \
        vb_ = pkfma(wo4, q7_, vb_); vb_ = pkfma(wo5, q8_, vb_); \
        float a0_ = (va_.x + va_.y) + wA12s * q6_.x; \
        float a1_ = (vb_.x + vb_.y) + wA0s * q2_.y; \
        float m0_ = (M1A)[(j)], mm_ = (M1B)[(j)]; \
        float r0_ = (m0_ > 1.f) ? 1.f : 0.f; \
        float r1_ = (mm_ > 1.f) ? 1.f : 0.f; \
        m0_ = 0.9f * m0_ + (a0_ + bA) - r0_; \
        mm_ = 0.9f * mm_ + (a1_ + bA) - r1_; \
        (M1A)[(j)] = m0_; (M1B)[(j)] = mm_; \
        (SPOOLH)[((ca >> 1) * RS + 1 + p_) * 2 + (ca & 1)] = \
            (m0_ > 1.f || mm_ > 1.f) ? 1.f : 0.f; \
    } }

// ===== phase B window: 7 v2f taps, 4 channels, PACKED dpp reduce; owner per COND =====
#define B_WIN(WB, COND, MSLOT, SPK) { \
    v2f t0_ = (WB)[0], t1_ = (WB)[1], t2v_ = (WB)[2], t3_ = (WB)[3], \
        t4_ = (WB)[4], t5_ = (WB)[5], t6_ = (WB)[6]; \
    v2f a0_ = {0.f, 0.f}, a1_ = {0.f, 0.f}, a2_ = {0.f, 0.f}, a3_ = {0.f, 0.f}; \
    a0_ = pkfma(wp0[0], t0_, a0_); a1_ = pkfma(wp1[0], t0_, a1_); \
    a2_ = pkfma(wp2[0], t0_, a2_); a3_ = pkfma(wp3[0], t0_, a3_); \
    a0_ = pkfma(wp0[1], t1_, a0_); a1_ = pkfma(wp1[1], t1_, a1_); \
    a2_ = pkfma(wp2[1], t1_, a2_); a3_ = pkfma(wp3[1], t1_, a3_); \
    a0_ = pkfma(wp0[2], t2v_, a0_); a1_ = pkfma(wp1[2], t2v_, a1_); \
    a2_ = pkfma(wp2[2], t2v_, a2_); a3_ = pkfma(wp3[2], t2v_, a3_); \
    a0_ = pkfma(wp0[3], t3_, a0_); a1_ = pkfma(wp1[3], t3_, a1_); \
    a2_ = pkfma(wp2[3], t3_, a2_); a3_ = pkfma(wp3[3], t3_, a3_); \
    a0_ = pkfma(wp0[4], t4_, a0_); a1_ = pkfma(wp1[4], t4_, a1_); \
    a2_ = pkfma(wp2[4], t4_, a2_); a3_ = pkfma(wp3[4], t4_, a3_); \
    a0_ = pkfma(wp0[5], t5_, a0_); a1_ = pkfma(wp1[5], t5_, a1_); \
    a2_ = pkfma(wp2[5], t5_, a2_); a3_ = pkfma(wp3[5], t5_, a3_); \
    a0_ = pkfma(wp0[6], t6_, a0_); a1_ = pkfma(wp1[6], t6_, a1_); \
    a2_ = pkfma(wp2[6], t6_, a2_); a3_ = pkfma(wp3[6], t6_, a3_); \
    v2f P01_, P23_; \
    P01_.x = a0_.x + a0_.y; P01_.y = a1_.x + a1_.y; \
    P23_.x = a2_.x + a2_.y; P23_.y = a3_.x + a3_.y; \
    P01_ = dpp_add8_pk(P01_); \
    P23_ = dpp_add8_pk(P23_); \
    float sc_ = (ccq == 0) ? P01_.x : ((ccq == 1) ? P01_.y : ((ccq == 2) ? P23_.x : P23_.y)); \
    if (COND) { \
        float mm_ = MSLOT; \
        float rr_ = (mm_ > 1.f) ? 1.f : 0.f; \
        mm_ = 0.9f * mm_ + (sc_ + bB) - rr_; \
        MSLOT = mm_; \
        SPK = (mm_ > 1.f) ? 1.f : 0.f; \
    } }

// ===== phase D: fc2 (32->2) + LIF4 + count =====
#define PHASE_D(SP3, M4, CNT) { \
    if (t2 < 64) { \
        float v = (SP3)[t2 & 31] * wD; \
        v += __shfl_xor(v, 16, 32); \
        v += __shfl_xor(v, 8, 32); \
        v += __shfl_xor(v, 4, 32); \
        v += __shfl_xor(v, 2, 32); \
        v += __shfl_xor(v, 1, 32); \
        if ((t2 & 31) == 0) { \
            float rr = (M4 > 1.f) ? 1.f : 0.f; \
            M4 = 0.9f * M4 + (v + bD) - rr; \
            if (M4 > 1.f) CNT += 1.f; \
        } \
    } }

    // ---- prologue: A(0) both samples ----
    A_J3(0, sx[0], spool2f[0], m1a0, m1b0)
    A_J3(1, sx[0], spool2f[0], m1a0, m1b0)
    A_J3(2, sx[0], spool2f[0], m1a0, m1b0)
    A_J3(0, sx[1], spool2f[1], m1a1, m1b1)
    A_J3(1, sx[1], spool2f[1], m1a1, m1b1)
    A_J3(2, sx[1], spool2f[1], m1a1, m1b1)
    __syncthreads();   // spool(0) ready

    for (int t = 0; t < NT; ++t) {
        // ===== interval I2: B(t) s0+s1 | D(t-1) s0+s1 | x(t+1) prefetch =====
        float xpA0 = 0.f, xpA1 = 0.f, xpB0 = 0.f, xpB1 = 0.f;
        if (t + 1 < NT) {
            const float* xt0 = xb0p + (size_t)(t + 1) * LIN;
            const float* xt1 = xb1p + (size_t)(t + 1) * LIN;
            xpA0 = xt0[t2];
            xpB0 = xt1[t2];
            if (t2 < LIN - 512) { xpA1 = xt0[t2 + 512]; xpB1 = xt1[t2 + 512]; }
        }

        float spkA0 = 0.f, spkB0 = 0.f, spkA1 = 0.f, spkB1 = 0.f;
        B_WIN(wbA,      ip < 4,  mA0, spkA0)
        B_WIN(wbA + 24, ip >= 4, mA0, spkA0)
        if (omh == 0 || og < 2) { B_WIN(wbA + 48, ip < 4, mB0, spkB0) }
        B_WIN(wbB,      ip < 4,  mA1, spkA1)
        B_WIN(wbB + 24, ip >= 4, mA1, spkA1)
        if (omh == 0 || og < 2) { B_WIN(wbB + 48, ip < 4, mB1, spkB1) }

        if (t > 0) {
            PHASE_D(sspk3[0], m4_0, cnt_0)
            PHASE_D(sspk3[1], m4_1, cnt_1)
        }

        // publish spikes
        {
            unsigned long long balA1 = __ballot(spkA0 > 0.5f);
            unsigned long long balA2 = __ballot(spkB0 > 0.5f);
            unsigned long long balB1 = __ballot(spkA1 > 0.5f);
            unsigned long long balB2 = __ballot(spkB1 > 0.5f);
            if (lane == 0) {
                sbits[0][wv][0] = balA1; sbits[0][wv][1] = balA2;
                sbits[1][wv][0] = balB1; sbits[1][wv][1] = balB2;
            }
        }

        // write x(t+1)
        if (t + 1 < NT) {
            sx[0][1 + t2] = xpA0;
            sx[1][1 + t2] = xpB0;
            if (t2 < LIN - 512) { sx[0][1 + t2 + 512] = xpA1; sx[1][1 + t2 + 512] = xpB1; }
        }
        __syncthreads();   // sbits(t) ready; spool(t) consumed; sx(t+1) ready

        // ===== interval I1: A(t+1) s0+s1 | C(t) s0+s1 (fused weight loads) =====
        if (t + 1 < NT) {
            A_J3(0, sx[0], spool2f[0], m1a0, m1b0)
            A_J3(1, sx[0], spool2f[0], m1a0, m1b0)
            A_J3(2, sx[0], spool2f[0], m1a0, m1b0)
            A_J3(0, sx[1], spool2f[1], m1a1, m1b1)
            A_J3(1, sx[1], spool2f[1], m1a1, m1b1)
            A_J3(2, sx[1], spool2f[1], m1a1, m1b1)
        }

        {
            unsigned long long M10 = sbits[0][q_][0] >> cc_;
            unsigned long long M20 = sbits[0][q_][1] >> cc_;
            unsigned long long M11 = sbits[1][q_][0] >> cc_;
            unsigned long long M21 = sbits[1][q_][1] >> cc_;
            uint32_t A1lo = (uint32_t)M10, A1hi = (uint32_t)(M10 >> 32);
            uint32_t A2lo = (uint32_t)M20, A2hi = (uint32_t)(M20 >> 32);
            uint32_t B1lo = (uint32_t)M11, B1hi = (uint32_t)(M11 >> 32);
            uint32_t B2lo = (uint32_t)M21, B2hi = (uint32_t)(M21 >> 32);

            v2f a0v0 = {0.f, 0.f}, a1v0 = {0.f, 0.f}, a0v1 = {0.f, 0.f}, a1v1 = {0.f, 0.f};
            #pragma unroll
            for (int i = 0; i < 11; ++i) {
                v2f f0, f1;
                f0.x = FBIT(A1lo, A1hi, A2lo, A2hi, 2 * i);
                f0.y = FBIT(A1lo, A1hi, A2lo, A2hi, 2 * i + 1);
                f1.x = FBIT(B1lo, B1hi, B2lo, B2hi, 2 * i);
                f1.y = FBIT(B1lo, B1hi, B2lo, B2hi, 2 * i + 1);
                float4 wa = wrow[i * 32];            // one load serves both samples
                a0v0 = pkfma((v2f){wa.x, wa.y}, f0, a0v0);
                a1v0 = pkfma((v2f){wa.z, wa.w}, f0, a1v0);
                a0v1 = pkfma((v2f){wa.x, wa.y}, f1, a0v1);
                a1v1 = pkfma((v2f){wa.z, wa.w}, f1, a1v1);
            }
            float a00 = red32(a0v0.x + a0v0.y);
            float a10 = red32(a1v0.x + a1v0.y);
            float a01 = red32(a0v1.x + a0v1.y);
            float a11 = red32(a1v1.x + a1v1.y);

            float r0 = (m30_0 > 1.f) ? 1.f : 0.f; m30_0 = 0.9f * m30_0 + (a00 + bC0) - r0;
            float r1 = (m31_0 > 1.f) ? 1.f : 0.f; m31_0 = 0.9f * m31_0 + (a10 + bC1) - r1;
            float r2 = (m30_1 > 1.f) ? 1.f : 0.f; m30_1 = 0.9f * m30_1 + (a01 + bC0) - r2;
            float r3 = (m31_1 > 1.f) ? 1.f : 0.f; m31_1 = 0.9f * m31_1 + (a11 + bC1) - r3;
            if (s_ == 0) {
                float2 st0, st1;
                st0.x = (m30_0 > 1.f) ? 1.f : 0.f;
                st0.y = (m31_0 > 1.f) ? 1.f : 0.f;
                st1.x = (m30_1 > 1.f) ? 1.f : 0.f;
                st1.y = (m31_1 > 1.f) ? 1.f : 0.f;
                *reinterpret_cast<float2*>(&sspk3[0][2 * gC]) = st0;
                *reinterpret_cast<float2*>(&sspk3[1][2 * gC]) = st1;
            }
        }
        __syncthreads();   // sspk3(t) ready for D in next I2; spool(t+1) ready
    }

    // ---- epilogue: D(NT-1) both samples ----
    PHASE_D(sspk3[0], m4_0, cnt_0)
    PHASE_D(sspk3[1], m4_1, cnt_1)

    if (t2 == 0)  { out[b0 * 2 + 0] = cnt_0; out[(b0 + 1) * 2 + 0] = cnt_1; }
    if (t2 == 32) { out[b0 * 2 + 1] = cnt_0; out[(b0 + 1) * 2 + 1] = cnt_1; }
}

extern "C" void kernel_launch(void* const* d_in, const int* in_sizes, int n_in,
                              void* d_out, int out_size, void* d_ws, size_t ws_size,
                              hipStream_t stream) {
    const float* x   = (const float*)d_in[0];
    const float* w1  = (const float*)d_in[1];
    const float* b1  = (const float*)d_in[2];
    const float* w2  = (const float*)d_in[3];
    const float* b2  = (const float*)d_in[4];
    const float* wf1 = (const float*)d_in[5];
    const float* bf1 = (const float*)d_in[6];
    const float* wf2 = (const float*)d_in[7];
    const float* bf2 = (const float*)d_in[8];
    float* out = (float*)d_out;

    snn_all<<<NB / 2, 512, 0, stream>>>(x, w1, b1, w2, b2, wf1, bf1, wf2, bf2, out);
}

// Round 18
// 358.661 us; speedup vs baseline: 1.0927x; 1.0927x over previous
//
#include <hip/hip_runtime.h>
#include <stdint.h>

// SNN audio classifier. Round 18 = round 16 (367us, best) with ONE change:
// phase A's odd-window conv1 sum restored to the v2f pairing form (wo0..wo5,
// round-15-verified): a1 = 6 pkfma + fma + add instead of 13 serial fmaf.
// Round 17's packed-dpp reduce is REVERTED (inline-asm pkadd blocked LLVM's
// DPP folding: 3 slots/stage vs fused 1 -> net regression, conflicts 5x).

#define NB 512
#define NT 100
#define LIN 686
#define RS 82          // spool row stride in v2f

typedef float v2f __attribute__((ext_vector_type(2)));

__device__ __forceinline__ v2f pkfma(v2f a, v2f b, v2f c) {
    v2f d;
    asm("v_pk_fma_f32 %0, %1, %2, %3" : "=v"(d) : "v"(a), "v"(b), "v"(c));
    return d;
}

__device__ __forceinline__ float dpp_add8(float x) {   // sum over 8-lane groups
    int t;
    t = __builtin_amdgcn_mov_dpp(__float_as_int(x), 0x141, 0xf, 0xf, true); // row_half_mirror
    x += __int_as_float(t);
    t = __builtin_amdgcn_mov_dpp(__float_as_int(x), 0x1B, 0xf, 0xf, true);  // quad_perm [3,2,1,0]
    x += __int_as_float(t);
    t = __builtin_amdgcn_mov_dpp(__float_as_int(x), 0xB1, 0xf, 0xf, true);  // quad_perm [1,0,3,2]
    x += __int_as_float(t);
    return x;
}

__device__ __forceinline__ float red32(float x) {      // sum over 32-lane groups
    int t;
    t = __builtin_amdgcn_mov_dpp(__float_as_int(x), 0xB1, 0xf, 0xf, true);  // xor1
    x += __int_as_float(t);
    t = __builtin_amdgcn_mov_dpp(__float_as_int(x), 0x4E, 0xf, 0xf, true);  // xor2
    x += __int_as_float(t);
    t = __builtin_amdgcn_mov_dpp(__float_as_int(x), 0x124, 0xf, 0xf, true); // row_ror:4
    x += __int_as_float(t);
    t = __builtin_amdgcn_mov_dpp(__float_as_int(x), 0x128, 0xf, 0xf, true); // row_ror:8
    x += __int_as_float(t);
    t = __builtin_amdgcn_ds_swizzle(__float_as_int(x), 0x401F);             // xor16
    x += __int_as_float(t);
    return x;
}

// bit(o) of the published spk2 ballots (512-thr layout, round-13-verified)
#define FBIT(W1L, W1H, W2L, W2H, o) \
    ((float)(((((o) < 16) ? ((((o) >> 2) & 1) ? (W1H) : (W1L)) \
                          : ((((o) >> 2) & 1) ? (W2H) : (W2L))) >> \
              (((o) < 16) ? (4 * (((o) >> 3) & 1) + 8 * ((o) & 3)) : (8 * ((o) & 3)))) & 1u))

__global__
__attribute__((amdgpu_flat_work_group_size(512, 512)))
__attribute__((amdgpu_waves_per_eu(1, 2)))
void snn_all(
    const float* __restrict__ x,
    const float* __restrict__ w1, const float* __restrict__ b1,
    const float* __restrict__ w2, const float* __restrict__ b2,
    const float* __restrict__ wf1, const float* __restrict__ bf1,
    const float* __restrict__ wf2, const float* __restrict__ bf2,
    float* __restrict__ out)
{
    __shared__ __align__(16) float swf1r[5632 * 4];            // 90112 B, shared
    __shared__ __align__(16) float sx[2][LIN + 2];
    __shared__ __align__(16) float spool2f[2][8 * RS * 2];
    __shared__ unsigned long long sbits[2][8][2];
    __shared__ __align__(8) float sspk3[2][32];

    const int t2   = threadIdx.x;      // 0..511
    const int b0   = blockIdx.x * 2;   // this block's two samples
    const int lane = t2 & 63;
    const int wv   = t2 >> 6;          // wave 0..7

    // ---------------- one-time init: reorder wf1 into LDS ----------------
    for (int d = t2; d < 5632; d += 512) {
        int g = d / 352;
        int r = d - g * 352;
        int i = r >> 5;
        int s = r & 31;
        float4 v;
        v.x = wf1[(2 * g)     * 704 + s * 22 + 2 * i];
        v.y = wf1[(2 * g)     * 704 + s * 22 + 2 * i + 1];
        v.z = wf1[(2 * g + 1) * 704 + s * 22 + 2 * i];
        v.w = wf1[(2 * g + 1) * 704 + s * 22 + 2 * i + 1];
        reinterpret_cast<float4*>(swf1r)[d] = v;
    }

    // ---- phase A setup: conv1. thread = (ca = t2&15, pg = t2>>4 in 0..31) ----
    const int ca = t2 & 15;
    const int pg = t2 >> 4;
    float wAs[13];
    #pragma unroll
    for (int k = 0; k < 13; ++k) wAs[k] = w1[ca * 13 + k];
    v2f we0 = {wAs[0], wAs[1]}, we1 = {wAs[2], wAs[3]}, we2 = {wAs[4], wAs[5]},
        we3 = {wAs[6], wAs[7]}, we4 = {wAs[8], wAs[9]}, we5 = {wAs[10], wAs[11]};
    v2f wo0 = {wAs[1], wAs[2]}, wo1 = {wAs[3], wAs[4]}, wo2 = {wAs[5], wAs[6]},
        wo3 = {wAs[7], wAs[8]}, wo4 = {wAs[9], wAs[10]}, wo5 = {wAs[11], wAs[12]};
    const float wA0s = wAs[0], wA12s = wAs[12];
    const float bA = b1[ca];
    float m1a0[3], m1b0[3], m1a1[3], m1b1[3];
    #pragma unroll
    for (int j = 0; j < 3; ++j) { m1a0[j] = 0.f; m1b0[j] = 0.f; m1a1[j] = 0.f; m1b1[j] = 0.f; }

    // ---- phase B setup: conv2. wave wv owns channel quartet 4wv..4wv+3 ----
    const int ip  = lane & 7;          // row-pair (conv1 rows 2ip, 2ip+1)
    const int og  = (lane >> 3) & 3;   // output phase
    const int omh = lane >> 5;         // window triple: om = {omh, 2+omh, 4+omh}
    const int ccq = ip & 3;            // owned channel within quartet
    v2f wp0[7], wp1[7], wp2[7], wp3[7];
    #pragma unroll
    for (int k = 0; k < 7; ++k) {
        int base0 = (wv * 4 + 0) * 112 + 14 * ip + k;
        int base1 = (wv * 4 + 1) * 112 + 14 * ip + k;
        int base2 = (wv * 4 + 2) * 112 + 14 * ip + k;
        int base3 = (wv * 4 + 3) * 112 + 14 * ip + k;
        wp0[k].x = w2[base0]; wp0[k].y = w2[base0 + 7];
        wp1[k].x = w2[base1]; wp1[k].y = w2[base1 + 7];
        wp2[k].x = w2[base2]; wp2[k].y = w2[base2 + 7];
        wp3[k].x = w2[base3]; wp3[k].y = w2[base3 + 7];
    }
    const float bB = b2[wv * 4 + ccq];
    float mA0 = 0.f, mB0 = 0.f, mA1 = 0.f, mB1 = 0.f;

    // ---- phase C setup: group gC = wv*2 + sub handles outputs 2gC, 2gC+1 ----
    const int sub = (t2 >> 5) & 1;
    const int gC  = wv * 2 + sub;
    const int s_  = t2 & 31;
    const float bC0 = bf1[2 * gC], bC1 = bf1[2 * gC + 1];
    float m30_0 = 0.f, m31_0 = 0.f, m30_1 = 0.f, m31_1 = 0.f;
    const int q_  = s_ >> 2;
    const int cc_ = s_ & 3;

    // ---- phase D setup: fc2 ----
    float wD = 0.f, bD = 0.f;
    if (t2 < 64) {
        wD = wf2[(t2 >> 5) * 32 + (t2 & 31)];
        if ((t2 & 31) == 0) bD = bf2[t2 >> 5];
    }
    float m4_0 = 0.f, cnt_0 = 0.f, m4_1 = 0.f, cnt_1 = 0.f;

    // ---- init LDS ----
    for (int i = t2; i < 2 * 8 * RS * 2; i += 512) ((float*)spool2f)[i] = 0.f;
    const float* xb0p = x + (size_t)b0 * NT * LIN;
    const float* xb1p = xb0p + (size_t)NT * LIN;
    if (t2 == 0) { sx[0][0] = 0.f; sx[0][LIN + 1] = 0.f; sx[1][0] = 0.f; sx[1][LIN + 1] = 0.f; }
    sx[0][1 + t2] = xb0p[t2];
    sx[1][1 + t2] = xb1p[t2];
    if (t2 < LIN - 512) {
        sx[0][1 + t2 + 512] = xb0p[t2 + 512];
        sx[1][1 + t2 + 512] = xb1p[t2 + 512];
    }
    __syncthreads();

    const v2f* sp0v = reinterpret_cast<const v2f*>(spool2f[0]);
    const v2f* sp1v = reinterpret_cast<const v2f*>(spool2f[1]);
    const v2f* wbA  = sp0v + ip * RS + 3 * og + 12 * omh;
    const v2f* wbB  = sp1v + ip * RS + 3 * og + 12 * omh;
    const float4* wrow = reinterpret_cast<const float4*>(swf1r) + gC * 352 + s_;

// ===== phase A (3-slot): conv1 + LIF1 + maxpool2, dual v2f pairings =====
#define A_J3(j, SXH, SPOOLH, M1A, M1B) { \
    const int p_ = ((j) == 2) ? (64 + pg) : (pg + 32 * (j)); \
    if ((j) < 2 || pg < 4) { \
        const v2f* qv_ = reinterpret_cast<const v2f*>((SXH) + 10 * p_); \
        v2f q0_ = qv_[0], q1_ = qv_[1], q2_ = qv_[2], q3_ = qv_[3], q4_ = qv_[4], \
            q5_ = qv_[5], q6_ = qv_[6], q7_ = qv_[7], q8_ = qv_[8]; \
        v2f va_ = {0.f, 0.f}, vb_ = {0.f, 0.f}; \
        va_ = pkfma(we0, q0_, va_); va_ = pkfma(we1, q1_, va_); \
        va_ = pkfma(we2, q2_, va_); va_ = pkfma(we3, q3_, va_); \
        va_ = pkfma(we4, q4_, va_); va_ = pkfma(we5, q5_, va_); \
        vb_ = pkfma(wo0, q3_, vb_); vb_ = pkfma(wo1, q4_, vb_); \
        vb_ = pkfma(wo2, q5_, vb_); vb_ = pkfma(wo3, q6_, vb_); \
        vb_ = pkfma(wo4, q7_, vb_); vb_ = pkfma(wo5, q8_, vb_); \
        float a0_ = (va_.x + va_.y) + wA12s * q6_.x; \
        float a1_ = (vb_.x + vb_.y) + wA0s * q2_.y; \
        float m0_ = (M1A)[(j)], mm_ = (M1B)[(j)]; \
        float r0_ = (m0_ > 1.f) ? 1.f : 0.f; \
        float r1_ = (mm_ > 1.f) ? 1.f : 0.f; \
        m0_ = 0.9f * m0_ + (a0_ + bA) - r0_; \
        mm_ = 0.9f * mm_ + (a1_ + bA) - r1_; \
        (M1A)[(j)] = m0_; (M1B)[(j)] = mm_; \
        (SPOOLH)[((ca >> 1) * RS + 1 + p_) * 2 + (ca & 1)] = \
            (m0_ > 1.f || mm_ > 1.f) ? 1.f : 0.f; \
    } }

// ===== phase B window: 7 v2f taps, 4 channels, scalar dpp reduce; owner per COND =====
#define B_WIN(WB, COND, MSLOT, SPK) { \
    v2f t0_ = (WB)[0], t1_ = (WB)[1], t2v_ = (WB)[2], t3_ = (WB)[3], \
        t4_ = (WB)[4], t5_ = (WB)[5], t6_ = (WB)[6]; \
    v2f a0_ = {0.f, 0.f}, a1_ = {0.f, 0.f}, a2_ = {0.f, 0.f}, a3_ = {0.f, 0.f}; \
    a0_ = pkfma(wp0[0], t0_, a0_); a1_ = pkfma(wp1[0], t0_, a1_); \
    a2_ = pkfma(wp2[0], t0_, a2_); a3_ = pkfma(wp3[0], t0_, a3_); \
    a0_ = pkfma(wp0[1], t1_, a0_); a1_ = pkfma(wp1[1], t1_, a1_); \
    a2_ = pkfma(wp2[1], t1_, a2_); a3_ = pkfma(wp3[1], t1_, a3_); \
    a0_ = pkfma(wp0[2], t2v_, a0_); a1_ = pkfma(wp1[2], t2v_, a1_); \
    a2_ = pkfma(wp2[2], t2v_, a2_); a3_ = pkfma(wp3[2], t2v_, a3_); \
    a0_ = pkfma(wp0[3], t3_, a0_); a1_ = pkfma(wp1[3], t3_, a1_); \
    a2_ = pkfma(wp2[3], t3_, a2_); a3_ = pkfma(wp3[3], t3_, a3_); \
    a0_ = pkfma(wp0[4], t4_, a0_); a1_ = pkfma(wp1[4], t4_, a1_); \
    a2_ = pkfma(wp2[4], t4_, a2_); a3_ = pkfma(wp3[4], t4_, a3_); \
    a0_ = pkfma(wp0[5], t5_, a0_); a1_ = pkfma(wp1[5], t5_, a1_); \
    a2_ = pkfma(wp2[5], t5_, a2_); a3_ = pkfma(wp3[5], t5_, a3_); \
    a0_ = pkfma(wp0[6], t6_, a0_); a1_ = pkfma(wp1[6], t6_, a1_); \
    a2_ = pkfma(wp2[6], t6_, a2_); a3_ = pkfma(wp3[6], t6_, a3_); \
    float s0_ = dpp_add8(a0_.x + a0_.y); \
    float s1_ = dpp_add8(a1_.x + a1_.y); \
    float s2_ = dpp_add8(a2_.x + a2_.y); \
    float s3_ = dpp_add8(a3_.x + a3_.y); \
    float sc_ = (ccq == 0) ? s0_ : ((ccq == 1) ? s1_ : ((ccq == 2) ? s2_ : s3_)); \
    if (COND) { \
        float mm_ = MSLOT; \
        float rr_ = (mm_ > 1.f) ? 1.f : 0.f; \
        mm_ = 0.9f * mm_ + (sc_ + bB) - rr_; \
        MSLOT = mm_; \
        SPK = (mm_ > 1.f) ? 1.f : 0.f; \
    } }

// ===== phase D: fc2 (32->2) + LIF4 + count =====
#define PHASE_D(SP3, M4, CNT) { \
    if (t2 < 64) { \
        float v = (SP3)[t2 & 31] * wD; \
        v += __shfl_xor(v, 16, 32); \
        v += __shfl_xor(v, 8, 32); \
        v += __shfl_xor(v, 4, 32); \
        v += __shfl_xor(v, 2, 32); \
        v += __shfl_xor(v, 1, 32); \
        if ((t2 & 31) == 0) { \
            float rr = (M4 > 1.f) ? 1.f : 0.f; \
            M4 = 0.9f * M4 + (v + bD) - rr; \
            if (M4 > 1.f) CNT += 1.f; \
        } \
    } }

    // ---- prologue: A(0) both samples ----
    A_J3(0, sx[0], spool2f[0], m1a0, m1b0)
    A_J3(1, sx[0], spool2f[0], m1a0, m1b0)
    A_J3(2, sx[0], spool2f[0], m1a0, m1b0)
    A_J3(0, sx[1], spool2f[1], m1a1, m1b1)
    A_J3(1, sx[1], spool2f[1], m1a1, m1b1)
    A_J3(2, sx[1], spool2f[1], m1a1, m1b1)
    __syncthreads();   // spool(0) ready

    for (int t = 0; t < NT; ++t) {
        // ===== interval I2: B(t) s0+s1 | D(t-1) s0+s1 | x(t+1) prefetch =====
        float xpA0 = 0.f, xpA1 = 0.f, xpB0 = 0.f, xpB1 = 0.f;
        if (t + 1 < NT) {
            const float* xt0 = xb0p + (size_t)(t + 1) * LIN;
            const float* xt1 = xb1p + (size_t)(t + 1) * LIN;
            xpA0 = xt0[t2];
            xpB0 = xt1[t2];
            if (t2 < LIN - 512) { xpA1 = xt0[t2 + 512]; xpB1 = xt1[t2 + 512]; }
        }

        float spkA0 = 0.f, spkB0 = 0.f, spkA1 = 0.f, spkB1 = 0.f;
        B_WIN(wbA,      ip < 4,  mA0, spkA0)
        B_WIN(wbA + 24, ip >= 4, mA0, spkA0)
        if (omh == 0 || og < 2) { B_WIN(wbA + 48, ip < 4, mB0, spkB0) }
        B_WIN(wbB,      ip < 4,  mA1, spkA1)
        B_WIN(wbB + 24, ip >= 4, mA1, spkA1)
        if (omh == 0 || og < 2) { B_WIN(wbB + 48, ip < 4, mB1, spkB1) }

        if (t > 0) {
            PHASE_D(sspk3[0], m4_0, cnt_0)
            PHASE_D(sspk3[1], m4_1, cnt_1)
        }

        // publish spikes
        {
            unsigned long long balA1 = __ballot(spkA0 > 0.5f);
            unsigned long long balA2 = __ballot(spkB0 > 0.5f);
            unsigned long long balB1 = __ballot(spkA1 > 0.5f);
            unsigned long long balB2 = __ballot(spkB1 > 0.5f);
            if (lane == 0) {
                sbits[0][wv][0] = balA1; sbits[0][wv][1] = balA2;
                sbits[1][wv][0] = balB1; sbits[1][wv][1] = balB2;
            }
        }

        // write x(t+1)
        if (t + 1 < NT) {
            sx[0][1 + t2] = xpA0;
            sx[1][1 + t2] = xpB0;
            if (t2 < LIN - 512) { sx[0][1 + t2 + 512] = xpA1; sx[1][1 + t2 + 512] = xpB1; }
        }
        __syncthreads();   // sbits(t) ready; spool(t) consumed; sx(t+1) ready

        // ===== interval I1: A(t+1) s0+s1 | C(t) s0+s1 (fused weight loads) =====
        if (t + 1 < NT) {
            A_J3(0, sx[0], spool2f[0], m1a0, m1b0)
            A_J3(1, sx[0], spool2f[0], m1a0, m1b0)
            A_J3(2, sx[0], spool2f[0], m1a0, m1b0)
            A_J3(0, sx[1], spool2f[1], m1a1, m1b1)
            A_J3(1, sx[1], spool2f[1], m1a1, m1b1)
            A_J3(2, sx[1], spool2f[1], m1a1, m1b1)
        }

        {
            unsigned long long M10 = sbits[0][q_][0] >> cc_;
            unsigned long long M20 = sbits[0][q_][1] >> cc_;
            unsigned long long M11 = sbits[1][q_][0] >> cc_;
            unsigned long long M21 = sbits[1][q_][1] >> cc_;
            uint32_t A1lo = (uint32_t)M10, A1hi = (uint32_t)(M10 >> 32);
            uint32_t A2lo = (uint32_t)M20, A2hi = (uint32_t)(M20 >> 32);
            uint32_t B1lo = (uint32_t)M11, B1hi = (uint32_t)(M11 >> 32);
            uint32_t B2lo = (uint32_t)M21, B2hi = (uint32_t)(M21 >> 32);

            v2f a0v0 = {0.f, 0.f}, a1v0 = {0.f, 0.f}, a0v1 = {0.f, 0.f}, a1v1 = {0.f, 0.f};
            #pragma unroll
            for (int i = 0; i < 11; ++i) {
                v2f f0, f1;
                f0.x = FBIT(A1lo, A1hi, A2lo, A2hi, 2 * i);
                f0.y = FBIT(A1lo, A1hi, A2lo, A2hi, 2 * i + 1);
                f1.x = FBIT(B1lo, B1hi, B2lo, B2hi, 2 * i);
                f1.y = FBIT(B1lo, B1hi, B2lo, B2hi, 2 * i + 1);
                float4 wa = wrow[i * 32];            // one load serves both samples
                a0v0 = pkfma((v2f){wa.x, wa.y}, f0, a0v0);
                a1v0 = pkfma((v2f){wa.z, wa.w}, f0, a1v0);
                a0v1 = pkfma((v2f){wa.x, wa.y}, f1, a0v1);
                a1v1 = pkfma((v2f){wa.z, wa.w}, f1, a1v1);
            }
            float a00 = red32(a0v0.x + a0v0.y);
            float a10 = red32(a1v0.x + a1v0.y);
            float a01 = red32(a0v1.x + a0v1.y);
            float a11 = red32(a1v1.x + a1v1.y);

            float r0 = (m30_0 > 1.f) ? 1.f : 0.f; m30_0 = 0.9f * m30_0 + (a00 + bC0) - r0;
            float r1 = (m31_0 > 1.f) ? 1.f : 0.f; m31_0 = 0.9f * m31_0 + (a10 + bC1) - r1;
            float r2 = (m30_1 > 1.f) ? 1.f : 0.f; m30_1 = 0.9f * m30_1 + (a01 + bC0) - r2;
            float r3 = (m31_1 > 1.f) ? 1.f : 0.f; m31_1 = 0.9f * m31_1 + (a11 + bC1) - r3;
            if (s_ == 0) {
                float2 st0, st1;
                st0.x = (m30_0 > 1.f) ? 1.f : 0.f;
                st0.y = (m31_0 > 1.f) ? 1.f : 0.f;
                st1.x = (m30_1 > 1.f) ? 1.f : 0.f;
                st1.y = (m31_1 > 1.f) ? 1.f : 0.f;
                *reinterpret_cast<float2*>(&sspk3[0][2 * gC]) = st0;
                *reinterpret_cast<float2*>(&sspk3[1][2 * gC]) = st1;
            }
        }
        __syncthreads();   // sspk3(t) ready for D in next I2; spool(t+1) ready
    }

    // ---- epilogue: D(NT-1) both samples ----
    PHASE_D(sspk3[0], m4_0, cnt_0)
    PHASE_D(sspk3[1], m4_1, cnt_1)

    if (t2 == 0)  { out[b0 * 2 + 0] = cnt_0; out[(b0 + 1) * 2 + 0] = cnt_1; }
    if (t2 == 32) { out[b0 * 2 + 1] = cnt_0; out[(b0 + 1) * 2 + 1] = cnt_1; }
}

extern "C" void kernel_launch(void* const* d_in, const int* in_sizes, int n_in,
                              void* d_out, int out_size, void* d_ws, size_t ws_size,
                              hipStream_t stream) {
    const float* x   = (const float*)d_in[0];
    const float* w1  = (const float*)d_in[1];
    const float* b1  = (const float*)d_in[2];
    const float* w2  = (const float*)d_in[3];
    const float* b2  = (const float*)d_in[4];
    const float* wf1 = (const float*)d_in[5];
    const float* bf1 = (const float*)d_in[6];
    const float* wf2 = (const float*)d_in[7];
    const float* bf2 = (const float*)d_in[8];
    float* out = (float*)d_out;

    snn_all<<<NB / 2, 512, 0, stream>>>(x, w1, b1, w2, b2, wf1, bf1, wf2, bf2, out);
}

// Round 19
// 339.383 us; speedup vs baseline: 1.1548x; 1.0568x over previous
//
#include <hip/hip_runtime.h>
#include <stdint.h>

// SNN audio classifier. Round 19 = round 18 (359us) with the ballot/bit path
// replaced by FLOAT spike publication: phase B owners write spk2 floats to
// sspk2F[sample][ch][o] (stride 26 -> conflict-free v2f reads); phase C reads
// 11 activation v2fs per sample from LDS instead of extracting 22 bits
// (~-90 VALU ops/lane-step on the 65%-busy pipe, +22 ops on the ~25% DS pipe).
// sbits/ballots/FBIT deleted. Everything else identical to round 18.

#define NB 512
#define NT 100
#define LIN 686
#define RS 82          // spool row stride in v2f
#define S2S 26         // sspk2F row stride in floats (13 v2f, odd -> 2-way free)

typedef float v2f __attribute__((ext_vector_type(2)));

__device__ __forceinline__ v2f pkfma(v2f a, v2f b, v2f c) {
    v2f d;
    asm("v_pk_fma_f32 %0, %1, %2, %3" : "=v"(d) : "v"(a), "v"(b), "v"(c));
    return d;
}

__device__ __forceinline__ float dpp_add8(float x) {   // sum over 8-lane groups
    int t;
    t = __builtin_amdgcn_mov_dpp(__float_as_int(x), 0x141, 0xf, 0xf, true); // row_half_mirror
    x += __int_as_float(t);
    t = __builtin_amdgcn_mov_dpp(__float_as_int(x), 0x1B, 0xf, 0xf, true);  // quad_perm [3,2,1,0]
    x += __int_as_float(t);
    t = __builtin_amdgcn_mov_dpp(__float_as_int(x), 0xB1, 0xf, 0xf, true);  // quad_perm [1,0,3,2]
    x += __int_as_float(t);
    return x;
}

__device__ __forceinline__ float red32(float x) {      // sum over 32-lane groups
    int t;
    t = __builtin_amdgcn_mov_dpp(__float_as_int(x), 0xB1, 0xf, 0xf, true);  // xor1
    x += __int_as_float(t);
    t = __builtin_amdgcn_mov_dpp(__float_as_int(x), 0x4E, 0xf, 0xf, true);  // xor2
    x += __int_as_float(t);
    t = __builtin_amdgcn_mov_dpp(__float_as_int(x), 0x124, 0xf, 0xf, true); // row_ror:4
    x += __int_as_float(t);
    t = __builtin_amdgcn_mov_dpp(__float_as_int(x), 0x128, 0xf, 0xf, true); // row_ror:8
    x += __int_as_float(t);
    t = __builtin_amdgcn_ds_swizzle(__float_as_int(x), 0x401F);             // xor16
    x += __int_as_float(t);
    return x;
}

__global__
__attribute__((amdgpu_flat_work_group_size(512, 512)))
__attribute__((amdgpu_waves_per_eu(1, 2)))
void snn_all(
    const float* __restrict__ x,
    const float* __restrict__ w1, const float* __restrict__ b1,
    const float* __restrict__ w2, const float* __restrict__ b2,
    const float* __restrict__ wf1, const float* __restrict__ bf1,
    const float* __restrict__ wf2, const float* __restrict__ bf2,
    float* __restrict__ out)
{
    __shared__ __align__(16) float swf1r[5632 * 4];            // 90112 B, shared
    __shared__ __align__(16) float sx[2][LIN + 2];
    __shared__ __align__(16) float spool2f[2][8 * RS * 2];
    __shared__ __align__(8)  float sspk2F[2][32 * S2S];        // 6656 B float spikes
    __shared__ __align__(8)  float sspk3[2][32];

    const int t2   = threadIdx.x;      // 0..511
    const int b0   = blockIdx.x * 2;   // this block's two samples
    const int lane = t2 & 63;
    const int wv   = t2 >> 6;          // wave 0..7

    // ---------------- one-time init: reorder wf1 into LDS ----------------
    for (int d = t2; d < 5632; d += 512) {
        int g = d / 352;
        int r = d - g * 352;
        int i = r >> 5;
        int s = r & 31;
        float4 v;
        v.x = wf1[(2 * g)     * 704 + s * 22 + 2 * i];
        v.y = wf1[(2 * g)     * 704 + s * 22 + 2 * i + 1];
        v.z = wf1[(2 * g + 1) * 704 + s * 22 + 2 * i];
        v.w = wf1[(2 * g + 1) * 704 + s * 22 + 2 * i + 1];
        reinterpret_cast<float4*>(swf1r)[d] = v;
    }

    // ---- phase A setup: conv1. thread = (ca = t2&15, pg = t2>>4 in 0..31) ----
    const int ca = t2 & 15;
    const int pg = t2 >> 4;
    float wAs[13];
    #pragma unroll
    for (int k = 0; k < 13; ++k) wAs[k] = w1[ca * 13 + k];
    v2f we0 = {wAs[0], wAs[1]}, we1 = {wAs[2], wAs[3]}, we2 = {wAs[4], wAs[5]},
        we3 = {wAs[6], wAs[7]}, we4 = {wAs[8], wAs[9]}, we5 = {wAs[10], wAs[11]};
    v2f wo0 = {wAs[1], wAs[2]}, wo1 = {wAs[3], wAs[4]}, wo2 = {wAs[5], wAs[6]},
        wo3 = {wAs[7], wAs[8]}, wo4 = {wAs[9], wAs[10]}, wo5 = {wAs[11], wAs[12]};
    const float wA0s = wAs[0], wA12s = wAs[12];
    const float bA = b1[ca];
    float m1a0[3], m1b0[3], m1a1[3], m1b1[3];
    #pragma unroll
    for (int j = 0; j < 3; ++j) { m1a0[j] = 0.f; m1b0[j] = 0.f; m1a1[j] = 0.f; m1b1[j] = 0.f; }

    // ---- phase B setup: conv2. wave wv owns channel quartet 4wv..4wv+3 ----
    const int ip  = lane & 7;          // row-pair (conv1 rows 2ip, 2ip+1)
    const int og  = (lane >> 3) & 3;   // output phase
    const int omh = lane >> 5;         // window triple: om = {omh, 2+omh, 4+omh}
    const int ccq = ip & 3;            // owned channel within quartet
    v2f wp0[7], wp1[7], wp2[7], wp3[7];
    #pragma unroll
    for (int k = 0; k < 7; ++k) {
        int base0 = (wv * 4 + 0) * 112 + 14 * ip + k;
        int base1 = (wv * 4 + 1) * 112 + 14 * ip + k;
        int base2 = (wv * 4 + 2) * 112 + 14 * ip + k;
        int base3 = (wv * 4 + 3) * 112 + 14 * ip + k;
        wp0[k].x = w2[base0]; wp0[k].y = w2[base0 + 7];
        wp1[k].x = w2[base1]; wp1[k].y = w2[base1 + 7];
        wp2[k].x = w2[base2]; wp2[k].y = w2[base2 + 7];
        wp3[k].x = w2[base3]; wp3[k].y = w2[base3 + 7];
    }
    const float bB = b2[wv * 4 + ccq];
    float mA0 = 0.f, mB0 = 0.f, mA1 = 0.f, mB1 = 0.f;
    float* sp2w0 = &sspk2F[0][(wv * 4 + ccq) * S2S];   // owner write base, sample 0
    float* sp2w1 = &sspk2F[1][(wv * 4 + ccq) * S2S];   // sample 1

    // ---- phase C setup: group gC = wv*2 + sub handles outputs 2gC, 2gC+1 ----
    const int sub = (t2 >> 5) & 1;
    const int gC  = wv * 2 + sub;
    const int s_  = t2 & 31;
    const float bC0 = bf1[2 * gC], bC1 = bf1[2 * gC + 1];
    float m30_0 = 0.f, m31_0 = 0.f, m30_1 = 0.f, m31_1 = 0.f;
    const v2f* sp2r0 = reinterpret_cast<const v2f*>(&sspk2F[0][s_ * S2S]);
    const v2f* sp2r1 = reinterpret_cast<const v2f*>(&sspk2F[1][s_ * S2S]);

    // ---- phase D setup: fc2 ----
    float wD = 0.f, bD = 0.f;
    if (t2 < 64) {
        wD = wf2[(t2 >> 5) * 32 + (t2 & 31)];
        if ((t2 & 31) == 0) bD = bf2[t2 >> 5];
    }
    float m4_0 = 0.f, cnt_0 = 0.f, m4_1 = 0.f, cnt_1 = 0.f;

    // ---- init LDS ----
    for (int i = t2; i < 2 * 8 * RS * 2; i += 512) ((float*)spool2f)[i] = 0.f;
    const float* xb0p = x + (size_t)b0 * NT * LIN;
    const float* xb1p = xb0p + (size_t)NT * LIN;
    if (t2 == 0) { sx[0][0] = 0.f; sx[0][LIN + 1] = 0.f; sx[1][0] = 0.f; sx[1][LIN + 1] = 0.f; }
    sx[0][1 + t2] = xb0p[t2];
    sx[1][1 + t2] = xb1p[t2];
    if (t2 < LIN - 512) {
        sx[0][1 + t2 + 512] = xb0p[t2 + 512];
        sx[1][1 + t2 + 512] = xb1p[t2 + 512];
    }
    __syncthreads();

    const v2f* sp0v = reinterpret_cast<const v2f*>(spool2f[0]);
    const v2f* sp1v = reinterpret_cast<const v2f*>(spool2f[1]);
    const v2f* wbA  = sp0v + ip * RS + 3 * og + 12 * omh;
    const v2f* wbB  = sp1v + ip * RS + 3 * og + 12 * omh;
    const float4* wrow = reinterpret_cast<const float4*>(swf1r) + gC * 352 + s_;

// ===== phase A (3-slot): conv1 + LIF1 + maxpool2, dual v2f pairings =====
#define A_J3(j, SXH, SPOOLH, M1A, M1B) { \
    const int p_ = ((j) == 2) ? (64 + pg) : (pg + 32 * (j)); \
    if ((j) < 2 || pg < 4) { \
        const v2f* qv_ = reinterpret_cast<const v2f*>((SXH) + 10 * p_); \
        v2f q0_ = qv_[0], q1_ = qv_[1], q2_ = qv_[2], q3_ = qv_[3], q4_ = qv_[4], \
            q5_ = qv_[5], q6_ = qv_[6], q7_ = qv_[7], q8_ = qv_[8]; \
        v2f va_ = {0.f, 0.f}, vb_ = {0.f, 0.f}; \
        va_ = pkfma(we0, q0_, va_); va_ = pkfma(we1, q1_, va_); \
        va_ = pkfma(we2, q2_, va_); va_ = pkfma(we3, q3_, va_); \
        va_ = pkfma(we4, q4_, va_); va_ = pkfma(we5, q5_, va_); \
        vb_ = pkfma(wo0, q3_, vb_); vb_ = pkfma(wo1, q4_, vb_); \
        vb_ = pkfma(wo2, q5_, vb_); vb_ = pkfma(wo3, q6_, vb_); \
        vb_ = pkfma(wo4, q7_, vb_); vb_ = pkfma(wo5, q8_, vb_); \
        float a0_ = (va_.x + va_.y) + wA12s * q6_.x; \
        float a1_ = (vb_.x + vb_.y) + wA0s * q2_.y; \
        float m0_ = (M1A)[(j)], mm_ = (M1B)[(j)]; \
        float r0_ = (m0_ > 1.f) ? 1.f : 0.f; \
        float r1_ = (mm_ > 1.f) ? 1.f : 0.f; \
        m0_ = 0.9f * m0_ + (a0_ + bA) - r0_; \
        mm_ = 0.9f * mm_ + (a1_ + bA) - r1_; \
        (M1A)[(j)] = m0_; (M1B)[(j)] = mm_; \
        (SPOOLH)[((ca >> 1) * RS + 1 + p_) * 2 + (ca & 1)] = \
            (m0_ > 1.f || mm_ > 1.f) ? 1.f : 0.f; \
    } }

// ===== phase B window: 7 v2f taps, 4 channels, scalar dpp reduce; owner per COND =====
#define B_WIN(WB, COND, MSLOT, SPK) { \
    v2f t0_ = (WB)[0], t1_ = (WB)[1], t2v_ = (WB)[2], t3_ = (WB)[3], \
        t4_ = (WB)[4], t5_ = (WB)[5], t6_ = (WB)[6]; \
    v2f a0_ = {0.f, 0.f}, a1_ = {0.f, 0.f}, a2_ = {0.f, 0.f}, a3_ = {0.f, 0.f}; \
    a0_ = pkfma(wp0[0], t0_, a0_); a1_ = pkfma(wp1[0], t0_, a1_); \
    a2_ = pkfma(wp2[0], t0_, a2_); a3_ = pkfma(wp3[0], t0_, a3_); \
    a0_ = pkfma(wp0[1], t1_, a0_); a1_ = pkfma(wp1[1], t1_, a1_); \
    a2_ = pkfma(wp2[1], t1_, a2_); a3_ = pkfma(wp3[1], t1_, a3_); \
    a0_ = pkfma(wp0[2], t2v_, a0_); a1_ = pkfma(wp1[2], t2v_, a1_); \
    a2_ = pkfma(wp2[2], t2v_, a2_); a3_ = pkfma(wp3[2], t2v_, a3_); \
    a0_ = pkfma(wp0[3], t3_, a0_); a1_ = pkfma(wp1[3], t3_, a1_); \
    a2_ = pkfma(wp2[3], t3_, a2_); a3_ = pkfma(wp3[3], t3_, a3_); \
    a0_ = pkfma(wp0[4], t4_, a0_); a1_ = pkfma(wp1[4], t4_, a1_); \
    a2_ = pkfma(wp2[4], t4_, a2_); a3_ = pkfma(wp3[4], t4_, a3_); \
    a0_ = pkfma(wp0[5], t5_, a0_); a1_ = pkfma(wp1[5], t5_, a1_); \
    a2_ = pkfma(wp2[5], t5_, a2_); a3_ = pkfma(wp3[5], t5_, a3_); \
    a0_ = pkfma(wp0[6], t6_, a0_); a1_ = pkfma(wp1[6], t6_, a1_); \
    a2_ = pkfma(wp2[6], t6_, a2_); a3_ = pkfma(wp3[6], t6_, a3_); \
    float s0_ = dpp_add8(a0_.x + a0_.y); \
    float s1_ = dpp_add8(a1_.x + a1_.y); \
    float s2_ = dpp_add8(a2_.x + a2_.y); \
    float s3_ = dpp_add8(a3_.x + a3_.y); \
    float sc_ = (ccq == 0) ? s0_ : ((ccq == 1) ? s1_ : ((ccq == 2) ? s2_ : s3_)); \
    if (COND) { \
        float mm_ = MSLOT; \
        float rr_ = (mm_ > 1.f) ? 1.f : 0.f; \
        mm_ = 0.9f * mm_ + (sc_ + bB) - rr_; \
        MSLOT = mm_; \
        SPK = (mm_ > 1.f) ? 1.f : 0.f; \
    } }

// ===== phase D: fc2 (32->2) + LIF4 + count =====
#define PHASE_D(SP3, M4, CNT) { \
    if (t2 < 64) { \
        float v = (SP3)[t2 & 31] * wD; \
        v += __shfl_xor(v, 16, 32); \
        v += __shfl_xor(v, 8, 32); \
        v += __shfl_xor(v, 4, 32); \
        v += __shfl_xor(v, 2, 32); \
        v += __shfl_xor(v, 1, 32); \
        if ((t2 & 31) == 0) { \
            float rr = (M4 > 1.f) ? 1.f : 0.f; \
            M4 = 0.9f * M4 + (v + bD) - rr; \
            if (M4 > 1.f) CNT += 1.f; \
        } \
    } }

    // ---- prologue: A(0) both samples ----
    A_J3(0, sx[0], spool2f[0], m1a0, m1b0)
    A_J3(1, sx[0], spool2f[0], m1a0, m1b0)
    A_J3(2, sx[0], spool2f[0], m1a0, m1b0)
    A_J3(0, sx[1], spool2f[1], m1a1, m1b1)
    A_J3(1, sx[1], spool2f[1], m1a1, m1b1)
    A_J3(2, sx[1], spool2f[1], m1a1, m1b1)
    __syncthreads();   // spool(0) ready

    for (int t = 0; t < NT; ++t) {
        // ===== interval I2: B(t) s0+s1 | D(t-1) s0+s1 | x(t+1) prefetch =====
        float xpA0 = 0.f, xpA1 = 0.f, xpB0 = 0.f, xpB1 = 0.f;
        if (t + 1 < NT) {
            const float* xt0 = xb0p + (size_t)(t + 1) * LIN;
            const float* xt1 = xb1p + (size_t)(t + 1) * LIN;
            xpA0 = xt0[t2];
            xpB0 = xt1[t2];
            if (t2 < LIN - 512) { xpA1 = xt0[t2 + 512]; xpB1 = xt1[t2 + 512]; }
        }

        float spkA0 = 0.f, spkB0 = 0.f, spkA1 = 0.f, spkB1 = 0.f;
        B_WIN(wbA,      ip < 4,  mA0, spkA0)
        B_WIN(wbA + 24, ip >= 4, mA0, spkA0)
        if (omh == 0 || og < 2) { B_WIN(wbA + 48, ip < 4, mB0, spkB0) }
        B_WIN(wbB,      ip < 4,  mA1, spkA1)
        B_WIN(wbB + 24, ip >= 4, mA1, spkA1)
        if (omh == 0 || og < 2) { B_WIN(wbB + 48, ip < 4, mB1, spkB1) }

        if (t > 0) {
            PHASE_D(sspk3[0], m4_0, cnt_0)
            PHASE_D(sspk3[1], m4_1, cnt_1)
        }

        // publish spk2 as FLOATS: owners cover all 22 outputs exactly once
        if (ip < 4) {
            sp2w0[og + 4 * omh] = spkA0;               // o in 0..7
            sp2w1[og + 4 * omh] = spkA1;
            if (omh == 0 || og < 2) {
                sp2w0[og + 16 + 4 * omh] = spkB0;      // o in 16..21
                sp2w1[og + 16 + 4 * omh] = spkB1;
            }
        } else {
            sp2w0[og + 8 + 4 * omh] = spkA0;           // o in 8..15
            sp2w1[og + 8 + 4 * omh] = spkA1;
        }

        // write x(t+1)
        if (t + 1 < NT) {
            sx[0][1 + t2] = xpA0;
            sx[1][1 + t2] = xpB0;
            if (t2 < LIN - 512) { sx[0][1 + t2 + 512] = xpA1; sx[1][1 + t2 + 512] = xpB1; }
        }
        __syncthreads();   // sspk2F(t) ready; spool(t) consumed; sx(t+1) ready

        // ===== interval I1: A(t+1) s0+s1 | C(t) s0+s1 (float activations) =====
        if (t + 1 < NT) {
            A_J3(0, sx[0], spool2f[0], m1a0, m1b0)
            A_J3(1, sx[0], spool2f[0], m1a0, m1b0)
            A_J3(2, sx[0], spool2f[0], m1a0, m1b0)
            A_J3(0, sx[1], spool2f[1], m1a1, m1b1)
            A_J3(1, sx[1], spool2f[1], m1a1, m1b1)
            A_J3(2, sx[1], spool2f[1], m1a1, m1b1)
        }

        {
            v2f a0v0 = {0.f, 0.f}, a1v0 = {0.f, 0.f}, a0v1 = {0.f, 0.f}, a1v1 = {0.f, 0.f};
            #pragma unroll
            for (int i = 0; i < 11; ++i) {
                v2f f0 = sp2r0[i];
                v2f f1 = sp2r1[i];
                float4 wa = wrow[i * 32];            // one load serves both samples
                a0v0 = pkfma((v2f){wa.x, wa.y}, f0, a0v0);
                a1v0 = pkfma((v2f){wa.z, wa.w}, f0, a1v0);
                a0v1 = pkfma((v2f){wa.x, wa.y}, f1, a0v1);
                a1v1 = pkfma((v2f){wa.z, wa.w}, f1, a1v1);
            }
            float a00 = red32(a0v0.x + a0v0.y);
            float a10 = red32(a1v0.x + a1v0.y);
            float a01 = red32(a0v1.x + a0v1.y);
            float a11 = red32(a1v1.x + a1v1.y);

            float r0 = (m30_0 > 1.f) ? 1.f : 0.f; m30_0 = 0.9f * m30_0 + (a00 + bC0) - r0;
            float r1 = (m31_0 > 1.f) ? 1.f : 0.f; m31_0 = 0.9f * m31_0 + (a10 + bC1) - r1;
            float r2 = (m30_1 > 1.f) ? 1.f : 0.f; m30_1 = 0.9f * m30_1 + (a01 + bC0) - r2;
            float r3 = (m31_1 > 1.f) ? 1.f : 0.f; m31_1 = 0.9f * m31_1 + (a11 + bC1) - r3;
            if (s_ == 0) {
                float2 st0, st1;
                st0.x = (m30_0 > 1.f) ? 1.f : 0.f;
                st0.y = (m31_0 > 1.f) ? 1.f : 0.f;
                st1.x = (m30_1 > 1.f) ? 1.f : 0.f;
                st1.y = (m31_1 > 1.f) ? 1.f : 0.f;
                *reinterpret_cast<float2*>(&sspk3[0][2 * gC]) = st0;
                *reinterpret_cast<float2*>(&sspk3[1][2 * gC]) = st1;
            }
        }
        __syncthreads();   // sspk3(t) ready for D in next I2; spool(t+1) ready
    }

    // ---- epilogue: D(NT-1) both samples ----
    PHASE_D(sspk3[0], m4_0, cnt_0)
    PHASE_D(sspk3[1], m4_1, cnt_1)

    if (t2 == 0)  { out[b0 * 2 + 0] = cnt_0; out[(b0 + 1) * 2 + 0] = cnt_1; }
    if (t2 == 32) { out[b0 * 2 + 1] = cnt_0; out[(b0 + 1) * 2 + 1] = cnt_1; }
}

extern "C" void kernel_launch(void* const* d_in, const int* in_sizes, int n_in,
                              void* d_out, int out_size, void* d_ws, size_t ws_size,
                              hipStream_t stream) {
    const float* x   = (const float*)d_in[0];
    const float* w1  = (const float*)d_in[1];
    const float* b1  = (const float*)d_in[2];
    const float* w2  = (const float*)d_in[3];
    const float* b2  = (const float*)d_in[4];
    const float* wf1 = (const float*)d_in[5];
    const float* bf1 = (const float*)d_in[6];
    const float* wf2 = (const float*)d_in[7];
    const float* bf2 = (const float*)d_in[8];
    float* out = (float*)d_out;

    snn_all<<<NB / 2, 512, 0, stream>>>(x, w1, b1, w2, b2, wf1, bf1, wf2, bf2, out);
}